// Round 1
// baseline (204.715 us; speedup 1.0000x reference)
//
#include <hip/hip_runtime.h>
#include <math.h>

// Problem constants
#define BB 8
#define CC 64
#define HH 256
#define WW 256
#define HP 257            // pooled / output spatial (H+1)
#define PADW 261          // HP + 4 (2-pad each side for 5x5 stencil)
#define NPB (HP * HP)     // 66049 outputs per batch
#define NBLK ((NPB + 255) / 256)   // 259 blocks per batch

// Workspace layout in floats:
//  [0, 2*BB*NBLK)              : per-block partial sums (sum, then sumsq)
//  [OFF_STATS, OFF_STATS+16)   : mu[8], rsig[8]
//  [OFF_S, +BB*HH*WW)          : channel sum s
//  [OFF_XSP, +BB*PADW*PADW)    : zero-padded pooled sum
#define OFF_PART 0
#define OFF_STATS (2 * BB * NBLK)
#define OFF_S 4352
#define OFF_XSP (OFF_S + BB * HH * WW)
// total ~1.07M floats (~4.3 MB) of d_ws

// ---- K1: channel sum over C=64, vectorized float4 ----
__global__ __launch_bounds__(256) void k_chansum(const float* __restrict__ x,
                                                 float* __restrict__ s) {
    int idx = blockIdx.x * 256 + threadIdx.x;       // [0, BB*HH*WW/4)
    int b = idx >> 14;                              // 16384 float4 per image
    int p = idx & 16383;
    const float4* xp = reinterpret_cast<const float4*>(x)
                       + (size_t)b * (CC * 16384) + p;
    float4 acc = make_float4(0.f, 0.f, 0.f, 0.f);
#pragma unroll 16
    for (int c = 0; c < CC; ++c) {
        float4 v = xp[(size_t)c * 16384];
        acc.x += v.x; acc.y += v.y; acc.z += v.z; acc.w += v.w;
    }
    reinterpret_cast<float4*>(s)[idx] = acc;
}

// ---- K2: 2x2 avg pool (stride 1, pad 1, count_include_pad) into padded buf ----
__global__ __launch_bounds__(256) void k_pool(const float* __restrict__ s,
                                              float* __restrict__ xsp) {
    int idx = blockIdx.x * 256 + threadIdx.x;
    if (idx >= BB * PADW * PADW) return;
    int b = idx / (PADW * PADW);
    int rem = idx % (PADW * PADW);
    int r = rem / PADW, cc = rem % PADW;
    float v = 0.f;
    if (r >= 2 && r < 2 + HP && cc >= 2 && cc < 2 + HP) {
        int i = r - 2, j = cc - 2;                  // 0..256
        const float* sb = s + b * (HH * WW);
        float v00 = (i >= 1      && j >= 1)      ? sb[(i - 1) * WW + (j - 1)] : 0.f;
        float v01 = (i >= 1      && j <= WW - 1) ? sb[(i - 1) * WW + j]       : 0.f;
        float v10 = (i <= HH - 1 && j >= 1)      ? sb[i * WW + (j - 1)]       : 0.f;
        float v11 = (i <= HH - 1 && j <= WW - 1) ? sb[i * WW + j]             : 0.f;
        v = 0.25f * (v00 + v01 + v10 + v11);
    }
    xsp[idx] = v;
}

// ---- folded 16-tap 5x5 stencil (the 8 shift-pairs x conv_w) ----
__device__ __forceinline__ float conv_y(const float* __restrict__ xb, int h, int w,
                                        const float* __restrict__ cw, float cb) {
    const float* p = xb + h * PADW + w;
    float y = cb;
    y -= cw[0] * p[0 * PADW + 0] + cw[1] * p[0 * PADW + 1] + cw[2] * p[0 * PADW + 2]
       + cw[3] * p[0 * PADW + 3] + cw[4] * p[0 * PADW + 4];
    y += cw[4] * p[4 * PADW + 0] + cw[3] * p[4 * PADW + 1] + cw[2] * p[4 * PADW + 2]
       + cw[1] * p[4 * PADW + 3] + cw[0] * p[4 * PADW + 4];
    y -= cw[5] * p[1 * PADW + 4] + cw[6] * p[2 * PADW + 4] + cw[7] * p[3 * PADW + 4];
    y += cw[7] * p[1 * PADW + 0] + cw[6] * p[2 * PADW + 0] + cw[5] * p[3 * PADW + 0];
    return y;
}

// ---- K3: stencil + per-block (sum, sumsq) partials ----
__global__ __launch_bounds__(256) void k_conv_part(const float* __restrict__ xsp,
                                                   const float* __restrict__ cw,
                                                   const float* __restrict__ cbp,
                                                   float* __restrict__ ws) {
    int b = blockIdx.y;
    int e = blockIdx.x * 256 + threadIdx.x;
    float y = 0.f;
    if (e < NPB) {
        int h = e / HP, w = e % HP;
        y = conv_y(xsp + b * (PADW * PADW), h, w, cw, cbp[0]);
    }
    float v1 = y, v2 = y * y;
    for (int off = 32; off > 0; off >>= 1) {
        v1 += __shfl_down(v1, off);
        v2 += __shfl_down(v2, off);
    }
    __shared__ float red[8];
    int lane = threadIdx.x & 63, wid = threadIdx.x >> 6;
    if (lane == 0) { red[wid] = v1; red[4 + wid] = v2; }
    __syncthreads();
    if (threadIdx.x == 0) {
        float s1 = red[0] + red[1] + red[2] + red[3];
        float s2 = red[4] + red[5] + red[6] + red[7];
        ws[OFF_PART + b * NBLK + blockIdx.x] = s1;
        ws[OFF_PART + BB * NBLK + b * NBLK + blockIdx.x] = s2;
    }
}

// ---- K4: finalize LN stats per batch ----
__global__ __launch_bounds__(256) void k_stats(float* __restrict__ ws) {
    int b = blockIdx.x;
    float v1 = 0.f, v2 = 0.f;
    for (int i = threadIdx.x; i < NBLK; i += 256) {
        v1 += ws[OFF_PART + b * NBLK + i];
        v2 += ws[OFF_PART + BB * NBLK + b * NBLK + i];
    }
    for (int off = 32; off > 0; off >>= 1) {
        v1 += __shfl_down(v1, off);
        v2 += __shfl_down(v2, off);
    }
    __shared__ float red[8];
    int lane = threadIdx.x & 63, wid = threadIdx.x >> 6;
    if (lane == 0) { red[wid] = v1; red[4 + wid] = v2; }
    __syncthreads();
    if (threadIdx.x == 0) {
        float s1 = red[0] + red[1] + red[2] + red[3];
        float s2 = red[4] + red[5] + red[6] + red[7];
        float mu = s1 / (float)NPB;
        float var = s2 / (float)NPB - mu * mu;
        float rsig = 1.0f / sqrtf(var + 1e-5f);
        ws[OFF_STATS + b] = mu;
        ws[OFF_STATS + 8 + b] = rsig;
    }
}

// ---- K5: recompute stencil, normalize, leaky-relu, store ----
__global__ __launch_bounds__(256) void k_final(const float* __restrict__ xsp,
                                               const float* __restrict__ cw,
                                               const float* __restrict__ cbp,
                                               const float* __restrict__ ws,
                                               float* __restrict__ out) {
    int b = blockIdx.y;
    int e = blockIdx.x * 256 + threadIdx.x;
    if (e >= NPB) return;
    int h = e / HP, w = e % HP;
    float y = conv_y(xsp + b * (PADW * PADW), h, w, cw, cbp[0]);
    float mu = ws[OFF_STATS + b];
    float rsig = ws[OFF_STATS + 8 + b];
    float z = (y - mu) * rsig;
    out[b * NPB + e] = (z >= 0.f) ? z : 0.01f * z;
}

extern "C" void kernel_launch(void* const* d_in, const int* in_sizes, int n_in,
                              void* d_out, int out_size, void* d_ws, size_t ws_size,
                              hipStream_t stream) {
    const float* x  = (const float*)d_in[0];   // [8,64,256,256]
    const float* cw = (const float*)d_in[1];   // [1,8]
    const float* cb = (const float*)d_in[2];   // [1]
    float* out = (float*)d_out;                // [8,1,257,257]
    float* ws  = (float*)d_ws;
    float* s   = ws + OFF_S;
    float* xsp = ws + OFF_XSP;

    k_chansum<<<(BB * HH * WW / 4) / 256, 256, 0, stream>>>(x, s);
    k_pool<<<(BB * PADW * PADW + 255) / 256, 256, 0, stream>>>(s, xsp);
    dim3 g3(NBLK, BB);
    k_conv_part<<<g3, 256, 0, stream>>>(xsp, cw, cb, ws);
    k_stats<<<BB, 256, 0, stream>>>(ws);
    k_final<<<g3, 256, 0, stream>>>(xsp, cw, cb, ws, out);
}

// Round 2
// 202.264 us; speedup vs baseline: 1.0121x; 1.0121x over previous
//
#include <hip/hip_runtime.h>
#include <math.h>

// Problem constants
#define BB 8
#define CC 64
#define HH 256
#define WW 256
#define HP 257                     // output spatial (H+1)
#define NPB (HP * HP)              // 66049 outputs per batch
#define NBLK ((NPB + 255) / 256)   // 259 blocks per batch

// Padded channel-sum buffer: rows -3..258 (262), cols -4..259+4 (stride 264,
// left pad 4 for float4 alignment, need >=3 each side for the 6x6 stencil).
#define SROWS 262
#define SSTR  264
#define SPIMG (SROWS * SSTR)       // 69168 floats per image

// Workspace layout (floats):
//  [0, 2*BB*NBLK)   per-block partials (sum, then sumsq)
//  [OFF_Y, +BB*NPB) conv output y
//  [OFF_SPAD, +BB*SPIMG) padded channel sum
#define OFF_PART 0
#define OFF_Y    4352
#define OFF_SPAD (OFF_Y + BB * NPB)   // 4352 + 528392 = 532744
// total 1,086,088 floats ~= 4.34 MB

#define N_INT (BB * 16384)         // interior float4 items
#define PAD_PER_IMG 908            // pad float4 items per image
#define N_TOT (N_INT + BB * PAD_PER_IMG)

// ---- K1: channel sum over C=64 into padded buffer; tail threads zero pads ----
__global__ __launch_bounds__(256) void k_chansum(const float* __restrict__ x,
                                                 float* __restrict__ ws) {
    int tid = blockIdx.x * 256 + threadIdx.x;
    float4* sp4 = reinterpret_cast<float4*>(ws + OFF_SPAD);
    if (tid < N_INT) {
        int b = tid >> 14;                  // 16384 float4 per image
        int p = tid & 16383;
        int i = p >> 6;                     // row 0..255 (64 float4 per row)
        int j4 = p & 63;
        const float4* xp = reinterpret_cast<const float4*>(x)
                           + (size_t)b * (CC * 16384) + p;
        float4 acc = make_float4(0.f, 0.f, 0.f, 0.f);
#pragma unroll 16
        for (int c = 0; c < CC; ++c) {
            float4 v = xp[(size_t)c * 16384];
            acc.x += v.x; acc.y += v.y; acc.z += v.z; acc.w += v.w;
        }
        // interior at padded (row i+3, float4-col 1+j4)
        sp4[b * (SPIMG / 4) + (i + 3) * (SSTR / 4) + 1 + j4] = acc;
    } else {
        int j = tid - N_INT;
        if (j < BB * PAD_PER_IMG) {
            int img = j / PAD_PER_IMG;
            int k = j % PAD_PER_IMG;
            int row, col4;
            if (k < 396) {                  // 3 top + 3 bottom full rows
                int r = k / 66;
                row = (r < 3) ? r : 256 + r;   // 0,1,2 / 259,260,261
                col4 = k % 66;
            } else {                        // side pads, rows 3..258
                int k2 = k - 396;
                row = 3 + (k2 >> 1);
                col4 = (k2 & 1) ? 65 : 0;
            }
            sp4[img * (SPIMG / 4) + row * (SSTR / 4) + col4] =
                make_float4(0.f, 0.f, 0.f, 0.f);
        }
    }
}

// ---- build combined 6x6 weights: (2x2 avg-pool) ∘ (16-tap 5x5 shift stencil) ----
__device__ __forceinline__ void build_w(const float* __restrict__ cw, float W[6][6]) {
    float T[5][5];
#pragma unroll
    for (int i = 0; i < 5; ++i)
#pragma unroll
        for (int j = 0; j < 5; ++j) T[i][j] = 0.f;
#pragma unroll
    for (int d = 0; d < 5; ++d) { T[0][d] = -cw[d]; T[4][d] = cw[4 - d]; }
    T[1][4] = -cw[5]; T[2][4] = -cw[6]; T[3][4] = -cw[7];
    T[1][0] =  cw[7]; T[2][0] =  cw[6]; T[3][0] =  cw[5];
#pragma unroll
    for (int u = 0; u < 6; ++u)
#pragma unroll
        for (int v = 0; v < 6; ++v) {
            float a = 0.f;
#pragma unroll
            for (int dr = u - 1; dr <= u; ++dr)
#pragma unroll
                for (int dc = v - 1; dc <= v; ++dc)
                    if (dr >= 0 && dr < 5 && dc >= 0 && dc < 5) a += T[dr][dc];
            W[u][v] = 0.25f * a;
        }
}

// ---- K2: 6x6 stencil on padded s -> y, plus per-block (sum,sumsq) partials ----
__global__ __launch_bounds__(256) void k_conv(float* __restrict__ ws,
                                              const float* __restrict__ cw,
                                              const float* __restrict__ cbp) {
    int b = blockIdx.y;
    int e = blockIdx.x * 256 + threadIdx.x;
    float W[6][6];
    build_w(cw, W);
    float y = 0.f;
    if (e < NPB) {
        int h = e / HP, w = e % HP;
        const float* p = ws + OFF_SPAD + b * SPIMG + h * SSTR + w + 1;
        float acc = cbp[0];
#pragma unroll
        for (int u = 0; u < 6; ++u)
#pragma unroll
            for (int v = 0; v < 6; ++v)
                acc += W[u][v] * p[u * SSTR + v];
        y = acc;
        ws[OFF_Y + b * NPB + e] = y;
    }
    float v1 = y, v2 = y * y;
    for (int off = 32; off > 0; off >>= 1) {
        v1 += __shfl_down(v1, off);
        v2 += __shfl_down(v2, off);
    }
    __shared__ float red[8];
    int lane = threadIdx.x & 63, wid = threadIdx.x >> 6;
    if (lane == 0) { red[wid] = v1; red[4 + wid] = v2; }
    __syncthreads();
    if (threadIdx.x == 0) {
        ws[OFF_PART + b * NBLK + blockIdx.x] = red[0] + red[1] + red[2] + red[3];
        ws[OFF_PART + BB * NBLK + b * NBLK + blockIdx.x] =
            red[4] + red[5] + red[6] + red[7];
    }
}

// ---- K3: per-block redundant stats reduce + normalize + leaky-relu ----
__global__ __launch_bounds__(256) void k_final(const float* __restrict__ ws,
                                               float* __restrict__ out) {
    int b = blockIdx.y;
    float v1 = 0.f, v2 = 0.f;
    for (int i = threadIdx.x; i < NBLK; i += 256) {
        v1 += ws[OFF_PART + b * NBLK + i];
        v2 += ws[OFF_PART + BB * NBLK + b * NBLK + i];
    }
    for (int off = 32; off > 0; off >>= 1) {
        v1 += __shfl_down(v1, off);
        v2 += __shfl_down(v2, off);
    }
    __shared__ float red[8];
    __shared__ float st[2];
    int lane = threadIdx.x & 63, wid = threadIdx.x >> 6;
    if (lane == 0) { red[wid] = v1; red[4 + wid] = v2; }
    __syncthreads();
    if (threadIdx.x == 0) {
        float s1 = red[0] + red[1] + red[2] + red[3];
        float s2 = red[4] + red[5] + red[6] + red[7];
        float mu = s1 / (float)NPB;
        float var = s2 / (float)NPB - mu * mu;
        st[0] = mu;
        st[1] = 1.0f / sqrtf(var + 1e-5f);
    }
    __syncthreads();
    float mu = st[0], rs = st[1];
    int e = blockIdx.x * 256 + threadIdx.x;
    if (e < NPB) {
        float z = (ws[OFF_Y + b * NPB + e] - mu) * rs;
        out[b * NPB + e] = (z >= 0.f) ? z : 0.01f * z;
    }
}

extern "C" void kernel_launch(void* const* d_in, const int* in_sizes, int n_in,
                              void* d_out, int out_size, void* d_ws, size_t ws_size,
                              hipStream_t stream) {
    const float* x  = (const float*)d_in[0];   // [8,64,256,256]
    const float* cw = (const float*)d_in[1];   // [1,8]
    const float* cb = (const float*)d_in[2];   // [1]
    float* out = (float*)d_out;                // [8,1,257,257]
    float* ws  = (float*)d_ws;

    k_chansum<<<(N_TOT + 255) / 256, 256, 0, stream>>>(x, ws);
    dim3 g(NBLK, BB);
    k_conv<<<g, 256, 0, stream>>>(ws, cw, cb);
    k_final<<<g, 256, 0, stream>>>(ws, out);
}